// Round 1
// 416.933 us; speedup vs baseline: 1.0911x; 1.0911x over previous
//
#include <hip/hip_runtime.h>
#include <cstdint>

typedef unsigned long long u64;
typedef float f4 __attribute__((ext_vector_type(4)));

constexpr int B = 4096;
constexpr int D = 8192;
constexpr int H = 4096;
constexpr int L = 128;
constexpr int DW = D / 64;   // 128 u64 words along d
constexpr int HW = H / 64;   // 64 u64 words along h
constexpr int RB = 4;        // rows per k_Z block (amortizes wbpw/cmin reads)

// ================= Kernel P: pack enc_weight rows ==========================
// Grid = H. Block h packs (ew[h][:] > 0.5) -> wbpw[w][H] (word-major).
// Nontemporal loads: ew is streamed exactly once, keep it out of L2.
__global__ __launch_bounds__(256) void k_P(const float* __restrict__ e,
                                           u64* __restrict__ wbpw) {
    __shared__ u64 sw[DW];                       // 1 KB
    unsigned char* sb = (unsigned char*)sw;
    int h = blockIdx.x;
    const f4* row4 = (const f4*)(e + (size_t)h * D);
    #pragma unroll
    for (int j = 0; j < 4; ++j) {
        int t = j * 256 + threadIdx.x;           // byte index [0, 1024)
        f4 a = __builtin_nontemporal_load(row4 + 2 * t);
        f4 c = __builtin_nontemporal_load(row4 + 2 * t + 1);
        unsigned v = (a.x > 0.5f ? 1u : 0u) | (a.y > 0.5f ? 2u : 0u)
                   | (a.z > 0.5f ? 4u : 0u) | (a.w > 0.5f ? 8u : 0u)
                   | (c.x > 0.5f ? 16u : 0u) | (c.y > 0.5f ? 32u : 0u)
                   | (c.z > 0.5f ? 64u : 0u) | (c.w > 0.5f ? 128u : 0u);
        sb[t] = (unsigned char)v;                // byte t = elements 8t..8t+7
    }
    __syncthreads();
    if (threadIdx.x < DW)
        wbpw[(size_t)threadIdx.x * H + h] = sw[threadIdx.x];
}

// ================= Kernel B: basef + cmin + clf row-sums ===================
// Blocks [0,128):    basef for d-word w via ballot colsums of wbpw
// Blocks [128,144):  cmin for 256 h each
// Blocks [144,272):  clf row-sum per l
__global__ __launch_bounds__(256) void k_B(const u64* __restrict__ wbpw,
                                           const float* __restrict__ bias0,
                                           const float* __restrict__ bias3,
                                           const float* __restrict__ clf,
                                           float* __restrict__ basef,
                                           int* __restrict__ cmin,
                                           float* __restrict__ R) {
    __shared__ int sc[4][64];
    __shared__ float s[256];
    int r = blockIdx.x;
    int lane = threadIdx.x & 63;
    int wave = threadIdx.x >> 6;
    if (r < DW) {
        int w = r;
        int cnt = 0;
        #pragma unroll 1
        for (int g = wave; g < 64; g += 4) {
            u64 W = wbpw[(size_t)w * H + g * 64 + lane];   // coalesced 512B
            #pragma unroll 1
            for (int jj = 0; jj < 64; ++jj) {
                u64 m = __ballot((int)((W >> jj) & 1ull));
                if (lane == jj) cnt += (int)__popcll(m);
            }
        }
        sc[wave][lane] = cnt;
        __syncthreads();
        if (wave == 0) {
            int tot = sc[0][lane] + sc[1][lane] + sc[2][lane] + sc[3][lane];
            int d = w * 64 + lane;
            basef[d] = ((float)tot + bias3[d] > 1.0f) ? 1.0f : 0.0f;
        }
    } else if (r < DW + 16) {
        // minimal integer c with (float)c + bias0[h] > 1.0f (exact fp32)
        int h = (r - DW) * 256 + threadIdx.x;
        float b0 = bias0[h];
        int c = (int)(1.0f - b0);
        if (c < 0) c = 0;
        int guard = 0;
        while ((float)c + b0 <= 1.0f && guard++ < 100000) ++c;
        while (c > 0 && (float)(c - 1) + b0 > 1.0f) --c;
        cmin[h] = c;
    } else {
        int l = r - (DW + 16);
        float acc = 0.f;
        for (int hh = threadIdx.x; hh < H; hh += 256) acc += clf[(size_t)l * H + hh];
        s[threadIdx.x] = acc;
        __syncthreads();
        for (int off = 128; off > 0; off >>= 1) {
            if ((int)threadIdx.x < off) s[threadIdx.x] += s[threadIdx.x + off];
            __syncthreads();
        }
        if (threadIdx.x == 0) R[l] = s[0];
    }
}

// ================= Kernel Z: RB rows per block, lazy-x probe ===============
// Only the first 256 columns of x are read (4 u64 words) — the branchless
// probe decides z for virtually every h; the rare tail ballot-packs further
// x words on demand directly from global. Output stores are nontemporal so
// the 194 MB write stream does not evict wbpw/cmin/basef from L2.
__global__ __launch_bounds__(256) void k_Z(const float* __restrict__ x,
                                           const u64* __restrict__ wbpw,
                                           const int* __restrict__ cmin,
                                           const float* __restrict__ basef,
                                           const float* __restrict__ R,
                                           const float* __restrict__ clf,
                                           const float* __restrict__ bias3,
                                           float* __restrict__ out0,
                                           float* __restrict__ out1,
                                           float* __restrict__ zout) {
    __shared__ u64 sxw4[RB][4];     // first 4 x-words per row
    __shared__ u64 zrow[RB][HW];
    __shared__ int s_nz[RB];
    int b0 = blockIdx.x * RB;
    int lane = threadIdx.x & 63;
    int wave = threadIdx.x >> 6;    // == row index for phases 0 and 2 (RB==4)

    // ---- phase 0: wave r ballot-packs first 4 words of row b0+r ----
    {
        const float* xr = x + (size_t)(b0 + wave) * D;
        #pragma unroll
        for (int j = 0; j < 4; ++j) {
            u64 m = __ballot(xr[j * 64 + lane] > 0.5f);
            if (lane == 0) sxw4[wave][j] = m;
        }
    }
    __syncthreads();
    u64 xa0[RB], xa1[RB], xa2[RB], xa3[RB];
    #pragma unroll
    for (int r = 0; r < RB; ++r) {
        xa0[r] = sxw4[r][0]; xa1[r] = sxw4[r][1];
        xa2[r] = sxw4[r][2]; xa3[r] = sxw4[r][3];
    }

    // ---- phase 1: z rows. One wbpw/cmin read serves RB rows. ----
    #pragma unroll 1
    for (int i = 0; i < HW / 4; ++i) {
        int hb = wave * (HW / 4) + i;
        int h = hb * 64 + lane;
        int cm = cmin[h];
        const u64* __restrict__ wp = wbpw + hb * 64 + lane;
        u64 w0 = wp[0];
        u64 w1 = wp[(size_t)H];
        u64 w2 = wp[(size_t)2 * H];
        u64 w3 = wp[(size_t)3 * H];
        #pragma unroll
        for (int r = 0; r < RB; ++r) {
            int cnt = (int)__popcll(xa0[r] & w0) + (int)__popcll(xa1[r] & w1)
                    + (int)__popcll(xa2[r] & w2) + (int)__popcll(xa3[r] & w3);
            if (!__all(cnt >= cm)) {            // P ~ 3e-5 per wave
                const float* xr = x + (size_t)(b0 + r) * D;
                #pragma unroll 1
                for (int w = 4; w < DW; ++w) {
                    u64 xm = __ballot(xr[w * 64 + lane] > 0.5f);
                    if (cnt < cm) cnt += (int)__popcll(xm & wp[(size_t)w * H]);
                    if (__all(cnt >= cm)) break;
                }
            }
            u64 m = __ballot(cnt >= cm);
            if (lane == 0) zrow[r][hb] = m;
        }
    }
    __syncthreads();

    // ---- phase 2: nz per row (wave r reduces row r) ----
    {
        int c = (int)__popcll(zrow[wave][lane]);
        #pragma unroll
        for (int off = 32; off > 0; off >>= 1) c += __shfl_down(c, off);
        if (lane == 0) s_nz[wave] = H - c;
    }
    __syncthreads();

    // ---- phase 3a: zout, coalesced nontemporal float4 from zrow bits ----
    #pragma unroll 1
    for (int r = 0; r < RB; ++r) {
        f4* zr = (f4*)(zout + (size_t)(b0 + r) * H);
        #pragma unroll
        for (int k = 0; k < 4; ++k) {
            int t = threadIdx.x + k * 256;     // float4 index in [0, H/4)
            u64 wzd = zrow[r][t >> 4];
            int j0 = (t & 15) * 4;
            f4 f;
            f.x = ((wzd >> (j0 + 0)) & 1ull) ? 1.0f : 0.0f;
            f.y = ((wzd >> (j0 + 1)) & 1ull) ? 1.0f : 0.0f;
            f.z = ((wzd >> (j0 + 2)) & 1ull) ? 1.0f : 0.0f;
            f.w = ((wzd >> (j0 + 3)) & 1ull) ? 1.0f : 0.0f;
            __builtin_nontemporal_store(f, zr + t);
        }
    }

    // ---- phase 3b: classification + recon output per row ----
    #pragma unroll 1
    for (int r = 0; r < RB; ++r) {
        int nz = s_nz[r];
        size_t bb = (size_t)(b0 + r);
        if (nz == 0) {
            if (threadIdx.x < L)
                __builtin_nontemporal_store(R[threadIdx.x], out1 + bb * L + threadIdx.x);
            f4* o4 = (f4*)(out0 + bb * D);
            const f4* b4 = (const f4*)basef;   // cached read, 32 KB broadcast
            #pragma unroll
            for (int k = 0; k < 8; ++k) {
                int t = threadIdx.x + k * 256; // [0, D/4)
                __builtin_nontemporal_store(b4[t], o4 + t);
            }
        } else {
            // ---- exact fallback (astronomically rare; correct, not fast) ----
            if (threadIdx.x < L) {
                int l = threadIdx.x;
                float acc = 0.f;
                for (int wh = 0; wh < HW; ++wh) {
                    u64 m = zrow[r][wh];
                    while (m) {
                        int j = __ffsll(m) - 1;
                        acc += clf[(size_t)l * H + wh * 64 + j];
                        m &= m - 1;
                    }
                }
                out1[bb * L + l] = acc;
            }
            // out0 via on-the-fly ballot transpose of wbpw masked by z.
            for (int w = wave; w < DW; w += 4) {
                int acc = 0;                      // count for d = w*64 + lane
                for (int hb = 0; hb < HW; ++hb) {
                    u64 Wj = wbpw[(size_t)w * H + hb * 64 + lane];
                    u64 zm = zrow[r][hb];
                    u64 masked = ((zm >> lane) & 1ull) ? Wj : 0ull;
                    for (int jj = 0; jj < 64; ++jj) {
                        u64 bal = __ballot((int)((masked >> jj) & 1ull));
                        if (lane == jj) acc += (int)__popcll(bal);
                    }
                }
                int d = w * 64 + lane;
                out0[bb * D + d] = ((float)acc + bias3[d] > 1.0f) ? 1.0f : 0.0f;
            }
        }
    }
}

// ================= launch ==================================================

extern "C" void kernel_launch(void* const* d_in, const int* in_sizes, int n_in,
                              void* d_out, int out_size, void* d_ws, size_t ws_size,
                              hipStream_t stream) {
    const float* x   = (const float*)d_in[0];
    const float* ew  = (const float*)d_in[1];
    const float* b0  = (const float*)d_in[2];
    const float* b3  = (const float*)d_in[3];
    const float* clf = (const float*)d_in[4];

    float* out0 = (float*)d_out;                 // [B][D]
    float* out1 = out0 + (size_t)B * D;          // [B][L]
    float* zout = out1 + (size_t)B * L;          // [B][H]

    char* ws = (char*)d_ws;
    u64* wbpw    = (u64*)(ws);                       // 4 MB
    float* basef = (float*)(ws + (4ull << 20));      // 32 KB
    float* R     = (float*)(ws + (4ull << 20) + 32768);        // 512 B
    int* cmin    = (int*)(ws + (4ull << 20) + 32768 + 512);    // 16 KB

    k_P<<<H, 256, 0, stream>>>(ew, wbpw);
    k_B<<<DW + 16 + L, 256, 0, stream>>>(wbpw, b0, b3, clf, basef, cmin, R);
    k_Z<<<B / RB, 256, 0, stream>>>(x, wbpw, cmin, basef, R, clf, b3,
                                    out0, out1, zout);
}

// Round 2
// 390.112 us; speedup vs baseline: 1.1661x; 1.0688x over previous
//
#include <hip/hip_runtime.h>
#include <cstdint>

typedef unsigned long long u64;
typedef float f4 __attribute__((ext_vector_type(4)));

constexpr int B = 4096;
constexpr int D = 8192;
constexpr int H = 4096;
constexpr int L = 128;
constexpr int DW = D / 64;   // 128 u64 words along d
constexpr int HW = H / 64;   // 64 u64 words along h
constexpr int RB = 4;        // rows per k_Z block (amortizes wbpw/cmin reads)

// ================= Kernel P: pack rows + cmin + clf row-sums ===============
// Blocks [0,H):       pack (ew[h][:] > 0.5) -> wbpw[w][H] (word-major)
// Blocks [H,H+16):    cmin for 256 h each        (independent of wbpw)
// Blocks [H+16,+128): clf row-sum per l          (independent of wbpw)
// The cmin/clf blocks overlap with the 128 MB ew stream instead of
// serializing behind it in a separate launch.
__global__ __launch_bounds__(256) void k_P(const float* __restrict__ e,
                                           const float* __restrict__ bias0,
                                           const float* __restrict__ clf,
                                           u64* __restrict__ wbpw,
                                           int* __restrict__ cmin,
                                           float* __restrict__ R) {
    __shared__ u64 sw[DW];                       // 1 KB
    __shared__ float s[256];
    int blk = blockIdx.x;
    if (blk < H) {
        unsigned char* sb = (unsigned char*)sw;
        int h = blk;
        const f4* row4 = (const f4*)(e + (size_t)h * D);
        #pragma unroll
        for (int j = 0; j < 4; ++j) {
            int t = j * 256 + threadIdx.x;       // byte index [0, 1024)
            f4 a = __builtin_nontemporal_load(row4 + 2 * t);
            f4 c = __builtin_nontemporal_load(row4 + 2 * t + 1);
            unsigned v = (a.x > 0.5f ? 1u : 0u) | (a.y > 0.5f ? 2u : 0u)
                       | (a.z > 0.5f ? 4u : 0u) | (a.w > 0.5f ? 8u : 0u)
                       | (c.x > 0.5f ? 16u : 0u) | (c.y > 0.5f ? 32u : 0u)
                       | (c.z > 0.5f ? 64u : 0u) | (c.w > 0.5f ? 128u : 0u);
            sb[t] = (unsigned char)v;            // byte t = elements 8t..8t+7
        }
        __syncthreads();
        if (threadIdx.x < DW)
            wbpw[(size_t)threadIdx.x * H + h] = sw[threadIdx.x];
    } else if (blk < H + 16) {
        // minimal integer c with (float)c + bias0[h] > 1.0f (exact fp32)
        int h = (blk - H) * 256 + threadIdx.x;
        float b0 = bias0[h];
        int c = (int)(1.0f - b0);
        if (c < 0) c = 0;
        int guard = 0;
        while ((float)c + b0 <= 1.0f && guard++ < 100000) ++c;
        while (c > 0 && (float)(c - 1) + b0 > 1.0f) --c;
        cmin[h] = c;
    } else {
        int l = blk - (H + 16);
        float acc = 0.f;
        for (int hh = threadIdx.x; hh < H; hh += 256) acc += clf[(size_t)l * H + hh];
        s[threadIdx.x] = acc;
        __syncthreads();
        for (int off = 128; off > 0; off >>= 1) {
            if ((int)threadIdx.x < off) s[threadIdx.x] += s[threadIdx.x + off];
            __syncthreads();
        }
        if (threadIdx.x == 0) R[l] = s[0];
    }
}

// ================= Kernel B: basef via bit-sliced column popcount ==========
// Grid = DW. Each lane CSA-accumulates its 16 h-words into 5 bit-planes
// (count <= 16 fits in 5 bits), then a 5-ballot-per-bit transpose replaces
// the old 64-ballot-per-word loop: 320 cross-lane ops/wave instead of 1024
// serial ballot rounds.
__global__ __launch_bounds__(256) void k_B(const u64* __restrict__ wbpw,
                                           const float* __restrict__ bias3,
                                           float* __restrict__ basef) {
    __shared__ int sc[4][64];
    int w = blockIdx.x;
    int lane = threadIdx.x & 63;
    int wave = threadIdx.x >> 6;
    u64 s0 = 0, s1 = 0, s2 = 0, s3 = 0, s4 = 0;
    #pragma unroll 1
    for (int g = wave; g < 64; g += 4) {
        u64 c = wbpw[(size_t)w * H + g * 64 + lane];   // coalesced 512B
        u64 t;
        t = s0 & c; s0 ^= c; c = t;
        t = s1 & c; s1 ^= c; c = t;
        t = s2 & c; s2 ^= c; c = t;
        t = s3 & c; s3 ^= c; c = t;
        s4 ^= c;                                  // max count 16 -> no carry out
    }
    int cnt = 0;
    #pragma unroll 1
    for (int jj = 0; jj < 64; ++jj) {
        int c = (int)__popcll(__ballot((int)((s0 >> jj) & 1ull)))
              + 2  * (int)__popcll(__ballot((int)((s1 >> jj) & 1ull)))
              + 4  * (int)__popcll(__ballot((int)((s2 >> jj) & 1ull)))
              + 8  * (int)__popcll(__ballot((int)((s3 >> jj) & 1ull)))
              + 16 * (int)__popcll(__ballot((int)((s4 >> jj) & 1ull)));
        if (lane == jj) cnt = c;
    }
    sc[wave][lane] = cnt;
    __syncthreads();
    if (wave == 0) {
        int tot = sc[0][lane] + sc[1][lane] + sc[2][lane] + sc[3][lane];
        int d = w * 64 + lane;
        basef[d] = ((float)tot + bias3[d] > 1.0f) ? 1.0f : 0.0f;
    }
}

// ================= Kernel Z: RB rows per block, lazy-x probe ===============
// Only the first 256 columns of x are read (4 u64 words) — the branchless
// probe decides z for virtually every h; the rare tail ballot-packs further
// x words on demand directly from global. Output stores are nontemporal so
// the 194 MB write stream does not evict wbpw/cmin/basef from L2.
__global__ __launch_bounds__(256) void k_Z(const float* __restrict__ x,
                                           const u64* __restrict__ wbpw,
                                           const int* __restrict__ cmin,
                                           const float* __restrict__ basef,
                                           const float* __restrict__ R,
                                           const float* __restrict__ clf,
                                           const float* __restrict__ bias3,
                                           float* __restrict__ out0,
                                           float* __restrict__ out1,
                                           float* __restrict__ zout) {
    __shared__ u64 sxw4[RB][4];     // first 4 x-words per row
    __shared__ u64 zrow[RB][HW];
    __shared__ int s_nz[RB];
    int b0 = blockIdx.x * RB;
    int lane = threadIdx.x & 63;
    int wave = threadIdx.x >> 6;    // == row index for phases 0 and 2 (RB==4)

    // ---- phase 0: wave r ballot-packs first 4 words of row b0+r ----
    {
        const float* xr = x + (size_t)(b0 + wave) * D;
        #pragma unroll
        for (int j = 0; j < 4; ++j) {
            u64 m = __ballot(xr[j * 64 + lane] > 0.5f);
            if (lane == 0) sxw4[wave][j] = m;
        }
    }
    __syncthreads();
    u64 xa0[RB], xa1[RB], xa2[RB], xa3[RB];
    #pragma unroll
    for (int r = 0; r < RB; ++r) {
        xa0[r] = sxw4[r][0]; xa1[r] = sxw4[r][1];
        xa2[r] = sxw4[r][2]; xa3[r] = sxw4[r][3];
    }

    // ---- phase 1: z rows. One wbpw/cmin read serves RB rows. ----
    #pragma unroll 1
    for (int i = 0; i < HW / 4; ++i) {
        int hb = wave * (HW / 4) + i;
        int h = hb * 64 + lane;
        int cm = cmin[h];
        const u64* __restrict__ wp = wbpw + hb * 64 + lane;
        u64 w0 = wp[0];
        u64 w1 = wp[(size_t)H];
        u64 w2 = wp[(size_t)2 * H];
        u64 w3 = wp[(size_t)3 * H];
        #pragma unroll
        for (int r = 0; r < RB; ++r) {
            int cnt = (int)__popcll(xa0[r] & w0) + (int)__popcll(xa1[r] & w1)
                    + (int)__popcll(xa2[r] & w2) + (int)__popcll(xa3[r] & w3);
            if (!__all(cnt >= cm)) {            // P ~ 3e-5 per wave
                const float* xr = x + (size_t)(b0 + r) * D;
                #pragma unroll 1
                for (int w = 4; w < DW; ++w) {
                    u64 xm = __ballot(xr[w * 64 + lane] > 0.5f);
                    if (cnt < cm) cnt += (int)__popcll(xm & wp[(size_t)w * H]);
                    if (__all(cnt >= cm)) break;
                }
            }
            u64 m = __ballot(cnt >= cm);
            if (lane == 0) zrow[r][hb] = m;
        }
    }
    __syncthreads();

    // ---- phase 2: nz per row (wave r reduces row r) ----
    {
        int c = (int)__popcll(zrow[wave][lane]);
        #pragma unroll
        for (int off = 32; off > 0; off >>= 1) c += __shfl_down(c, off);
        if (lane == 0) s_nz[wave] = H - c;
    }
    __syncthreads();

    // ---- phase 3a: zout, coalesced nontemporal float4 from zrow bits ----
    #pragma unroll 1
    for (int r = 0; r < RB; ++r) {
        f4* zr = (f4*)(zout + (size_t)(b0 + r) * H);
        #pragma unroll
        for (int k = 0; k < 4; ++k) {
            int t = threadIdx.x + k * 256;     // float4 index in [0, H/4)
            u64 wzd = zrow[r][t >> 4];
            int j0 = (t & 15) * 4;
            f4 f;
            f.x = ((wzd >> (j0 + 0)) & 1ull) ? 1.0f : 0.0f;
            f.y = ((wzd >> (j0 + 1)) & 1ull) ? 1.0f : 0.0f;
            f.z = ((wzd >> (j0 + 2)) & 1ull) ? 1.0f : 0.0f;
            f.w = ((wzd >> (j0 + 3)) & 1ull) ? 1.0f : 0.0f;
            __builtin_nontemporal_store(f, zr + t);
        }
    }

    // ---- phase 3b: classification + recon output per row ----
    #pragma unroll 1
    for (int r = 0; r < RB; ++r) {
        int nz = s_nz[r];
        size_t bb = (size_t)(b0 + r);
        if (nz == 0) {
            if (threadIdx.x < L)
                __builtin_nontemporal_store(R[threadIdx.x], out1 + bb * L + threadIdx.x);
            f4* o4 = (f4*)(out0 + bb * D);
            const f4* b4 = (const f4*)basef;   // cached read, 32 KB broadcast
            #pragma unroll
            for (int k = 0; k < 8; ++k) {
                int t = threadIdx.x + k * 256; // [0, D/4)
                __builtin_nontemporal_store(b4[t], o4 + t);
            }
        } else {
            // ---- exact fallback (astronomically rare; correct, not fast) ----
            if (threadIdx.x < L) {
                int l = threadIdx.x;
                float acc = 0.f;
                for (int wh = 0; wh < HW; ++wh) {
                    u64 m = zrow[r][wh];
                    while (m) {
                        int j = __ffsll(m) - 1;
                        acc += clf[(size_t)l * H + wh * 64 + j];
                        m &= m - 1;
                    }
                }
                out1[bb * L + l] = acc;
            }
            // out0 via on-the-fly ballot transpose of wbpw masked by z.
            for (int w = wave; w < DW; w += 4) {
                int acc = 0;                      // count for d = w*64 + lane
                for (int hb = 0; hb < HW; ++hb) {
                    u64 Wj = wbpw[(size_t)w * H + hb * 64 + lane];
                    u64 zm = zrow[r][hb];
                    u64 masked = ((zm >> lane) & 1ull) ? Wj : 0ull;
                    for (int jj = 0; jj < 64; ++jj) {
                        u64 bal = __ballot((int)((masked >> jj) & 1ull));
                        if (lane == jj) acc += (int)__popcll(bal);
                    }
                }
                int d = w * 64 + lane;
                out0[bb * D + d] = ((float)acc + bias3[d] > 1.0f) ? 1.0f : 0.0f;
            }
        }
    }
}

// ================= launch ==================================================

extern "C" void kernel_launch(void* const* d_in, const int* in_sizes, int n_in,
                              void* d_out, int out_size, void* d_ws, size_t ws_size,
                              hipStream_t stream) {
    const float* x   = (const float*)d_in[0];
    const float* ew  = (const float*)d_in[1];
    const float* b0  = (const float*)d_in[2];
    const float* b3  = (const float*)d_in[3];
    const float* clf = (const float*)d_in[4];

    float* out0 = (float*)d_out;                 // [B][D]
    float* out1 = out0 + (size_t)B * D;          // [B][L]
    float* zout = out1 + (size_t)B * L;          // [B][H]

    char* ws = (char*)d_ws;
    u64* wbpw    = (u64*)(ws);                       // 4 MB
    float* basef = (float*)(ws + (4ull << 20));      // 32 KB
    float* R     = (float*)(ws + (4ull << 20) + 32768);        // 512 B
    int* cmin    = (int*)(ws + (4ull << 20) + 32768 + 512);    // 16 KB

    k_P<<<H + 16 + L, 256, 0, stream>>>(ew, b0, clf, wbpw, cmin, R);
    k_B<<<DW, 256, 0, stream>>>(wbpw, b3, basef);
    k_Z<<<B / RB, 256, 0, stream>>>(x, wbpw, cmin, basef, R, clf, b3,
                                    out0, out1, zout);
}